// Round 6
// baseline (43.273 us; speedup 1.0000x reference)
//
#include <hip/hip_runtime.h>

#define B     512
#define NBG   10000
#define F     32
#define H     128
#define CHUNK 20
#define NBLK  500      // NBLK*CHUNK == NBG exactly
#define NP    10240    // padded row length for xbgT (pads never read)
#define RB    8        // batch rows per MLP block
#define MLPBLK (B / RB)     // 64
#define TRBLK  (NP / 128)   // 80

// ---------------- Kernel A: MLP (blocks 0..63) + xbg transpose (blocks 64..143) ----------------
__global__ __launch_bounds__(128) void prep_kernel(
    const float* __restrict__ X,
    const float* __restrict__ xbg,
    const float* __restrict__ W0, const float* __restrict__ b0,
    const float* __restrict__ W1, const float* __restrict__ b1,
    const float* __restrict__ Wout, const float* __restrict__ bout,
    float* __restrict__ XT,
    float* __restrict__ babsT,
    float* __restrict__ xbgT)
{
    __shared__ __align__(16) float lds[128 * 33];
    const int t = threadIdx.x;

    if (blockIdx.x < MLPBLK) {
        const int r0 = blockIdx.x * RB;
        float* xr = lds;                 // [RB][F]
        float* h0 = lds + RB * F;        // [RB][H]
        float* h1 = lds + RB * (F + H);  // [RB][H]

        for (int i = t; i < RB * F; i += 128) {
            int r = i >> 5, f = i & 31;
            float xv = X[(r0 + r) * F + f];
            xr[r * F + f] = xv;
            XT[f * B + r0 + r] = xv;
        }
        __syncthreads();

        float acc[RB];
        #pragma unroll
        for (int r = 0; r < RB; ++r) acc[r] = b0[t];
        #pragma unroll
        for (int f4 = 0; f4 < F / 4; ++f4) {
            float wa = W0[(4*f4+0)*H + t];
            float wb = W0[(4*f4+1)*H + t];
            float wc = W0[(4*f4+2)*H + t];
            float wd = W0[(4*f4+3)*H + t];
            #pragma unroll
            for (int r = 0; r < RB; ++r) {
                float4 xv = *(const float4*)&xr[r * F + 4*f4];
                acc[r] += xv.x*wa + xv.y*wb + xv.z*wc + xv.w*wd;
            }
        }
        #pragma unroll
        for (int r = 0; r < RB; ++r) h0[r * H + t] = fmaxf(acc[r], 0.f);
        __syncthreads();

        #pragma unroll
        for (int r = 0; r < RB; ++r) acc[r] = b1[t];
        #pragma unroll 8
        for (int j4 = 0; j4 < H / 4; ++j4) {
            float wa = W1[(4*j4+0)*H + t];
            float wb = W1[(4*j4+1)*H + t];
            float wc = W1[(4*j4+2)*H + t];
            float wd = W1[(4*j4+3)*H + t];
            #pragma unroll
            for (int r = 0; r < RB; ++r) {
                float4 hv = *(const float4*)&h0[r * H + 4*j4];
                acc[r] += hv.x*wa + hv.y*wb + hv.z*wc + hv.w*wd;
            }
        }
        #pragma unroll
        for (int r = 0; r < RB; ++r) h1[r * H + t] = fmaxf(acc[r], 0.f);
        __syncthreads();

        for (int i = t; i < RB * F; i += 128) {
            int r = i >> 5, f = i & 31;
            float a = bout[f];
            #pragma unroll 8
            for (int j4 = 0; j4 < H / 4; ++j4) {
                float4 hv = *(const float4*)&h1[r * H + 4*j4];
                a += hv.x*Wout[(4*j4+0)*F + f] + hv.y*Wout[(4*j4+1)*F + f]
                   + hv.z*Wout[(4*j4+2)*F + f] + hv.w*Wout[(4*j4+3)*F + f];
            }
            babsT[f * B + r0 + r] = fabsf(a);
        }
    } else {
        // transpose 128 points into xbgT[f][n] (pads never read)
        const int nb = (blockIdx.x - MLPBLK) * 128;

        #pragma unroll
        for (int k = 0; k < 32; ++k) {
            int idx = k * 128 + t;          // contiguous over xbg
            int nl  = idx >> 5;
            int f   = idx & 31;
            int n   = nb + nl;
            lds[nl * 33 + f] = (n < NBG) ? xbg[n * F + f] : 0.f;
        }
        __syncthreads();

        #pragma unroll
        for (int f = 0; f < F; ++f)
            xbgT[f * NP + nb + t] = lds[t * 33 + f];   // coalesced 512B stores
    }
}

// ---------------- Kernel B: NW partial sums ----------------
// Thread = batch row b. Block = chunk of CHUNK=20 background points.
// xq[32]/bv[32] preloaded ONCE (64 coalesced scalar loads) under a 128-VGPR
// budget (launch_bounds(512,4)); f x point loop fully unrolled -> steady state
// is pure VALU (v_sub + v_fma|abs|) + uniform s_loads hoisted ahead.
__global__ __launch_bounds__(512, 4) void nw_partial(
    const float* __restrict__ XT,
    const float* __restrict__ babsT,
    const float* __restrict__ xbgT,
    const float* __restrict__ ybg,
    float* __restrict__ psw,
    float* __restrict__ pswy)
{
    const int b  = threadIdx.x;
    const int n0 = blockIdx.x * CHUNK;

    float xq[F], bv[F];
    #pragma unroll
    for (int f = 0; f < F; ++f) {
        xq[f] = XT[f * B + b];          // coalesced 256B/wave, L2-resident
        bv[f] = babsT[f * B + b];
    }
    #pragma unroll
    for (int f = 0; f < F; ++f)
        asm volatile("" : "+v"(xq[f]), "+v"(bv[f]));   // keep in VGPRs

    float d[CHUNK];
    #pragma unroll
    for (int j = 0; j < CHUNK; ++j) d[j] = 0.f;

    #pragma unroll
    for (int f = 0; f < F; ++f) {
        const float* __restrict__ p = xbgT + f * NP + n0;   // uniform -> s_load
        #pragma unroll
        for (int j = 0; j < CHUNK; ++j)
            d[j] += bv[f] * fabsf(xq[f] - p[j]);
    }

    float sw = 0.f, swy = 0.f;
    const float* __restrict__ y = ybg + n0;                 // uniform -> s_load
    #pragma unroll
    for (int j = 0; j < CHUNK; ++j) {
        float w = __expf(-d[j]);
        sw  += w;
        swy += w * y[j];
    }

    psw [blockIdx.x * B + b] = sw;    // coalesced
    pswy[blockIdx.x * B + b] = swy;
}

// ---------------- Kernel C: combine partials, normalize ----------------
__global__ __launch_bounds__(64) void nw_final(
    const float* __restrict__ psw,
    const float* __restrict__ pswy,
    float* __restrict__ out)
{
    const int b = blockIdx.x;
    const int t = threadIdx.x;

    float sw = 0.f, swy = 0.f;
    for (int c = t; c < NBLK; c += 64) {
        sw  += psw [c * B + b];
        swy += pswy[c * B + b];
    }
    #pragma unroll
    for (int off = 32; off > 0; off >>= 1) {
        sw  += __shfl_down(sw,  off);
        swy += __shfl_down(swy, off);
    }
    if (t == 0) out[b] = swy / sw;
}

extern "C" void kernel_launch(void* const* d_in, const int* in_sizes, int n_in,
                              void* d_out, int out_size, void* d_ws, size_t ws_size,
                              hipStream_t stream)
{
    const float* X    = (const float*)d_in[0];
    const float* xbg  = (const float*)d_in[1];
    const float* ybg  = (const float*)d_in[2];
    const float* W0   = (const float*)d_in[3];
    const float* b0   = (const float*)d_in[4];
    const float* W1   = (const float*)d_in[5];
    const float* b1   = (const float*)d_in[6];
    const float* Wout = (const float*)d_in[7];
    const float* bout = (const float*)d_in[8];
    float* out = (float*)d_out;

    float* XT    = (float*)d_ws;              // F*B
    float* babsT = XT + F * B;                // F*B
    float* xbgT  = babsT + F * B;             // F*NP  (1.31 MB)
    float* psw   = xbgT + F * NP;             // NBLK*B (1 MB)
    float* pswy  = psw + NBLK * B;            // NBLK*B (1 MB)

    prep_kernel<<<MLPBLK + TRBLK, 128, 0, stream>>>(X, xbg, W0, b0, W1, b1,
                                                    Wout, bout, XT, babsT, xbgT);
    nw_partial<<<NBLK, B, 0, stream>>>(XT, babsT, xbgT, ybg, psw, pswy);
    nw_final<<<B, 64, 0, stream>>>(psw, pswy, out);
}

// Round 7
// 43.251 us; speedup vs baseline: 1.0005x; 1.0005x over previous
//
#include <hip/hip_runtime.h>

#define B     512
#define NBG   10000
#define F     32
#define H     128
#define CHUNK 20
#define NBLK  500      // NBLK*CHUNK == NBG exactly
#define RB    8        // batch rows per MLP block
#define MLPBLK (B / RB)     // 64

// ---------------- Kernel A: MLP -> XT[f][b], babsT[f][b] ----------------
__global__ __launch_bounds__(128) void prep_kernel(
    const float* __restrict__ X,
    const float* __restrict__ W0, const float* __restrict__ b0,
    const float* __restrict__ W1, const float* __restrict__ b1,
    const float* __restrict__ Wout, const float* __restrict__ bout,
    float* __restrict__ XT,
    float* __restrict__ babsT)
{
    __shared__ __align__(16) float xr[RB * F];
    __shared__ __align__(16) float h0[RB * H];
    __shared__ __align__(16) float h1[RB * H];
    const int t  = threadIdx.x;
    const int r0 = blockIdx.x * RB;

    for (int i = t; i < RB * F; i += 128) {
        int r = i >> 5, f = i & 31;
        float xv = X[(r0 + r) * F + f];
        xr[r * F + f] = xv;
        XT[f * B + r0 + r] = xv;
    }
    __syncthreads();

    float acc[RB];
    #pragma unroll
    for (int r = 0; r < RB; ++r) acc[r] = b0[t];
    #pragma unroll
    for (int f4 = 0; f4 < F / 4; ++f4) {
        float wa = W0[(4*f4+0)*H + t];
        float wb = W0[(4*f4+1)*H + t];
        float wc = W0[(4*f4+2)*H + t];
        float wd = W0[(4*f4+3)*H + t];
        #pragma unroll
        for (int r = 0; r < RB; ++r) {
            float4 xv = *(const float4*)&xr[r * F + 4*f4];
            acc[r] += xv.x*wa + xv.y*wb + xv.z*wc + xv.w*wd;
        }
    }
    #pragma unroll
    for (int r = 0; r < RB; ++r) h0[r * H + t] = fmaxf(acc[r], 0.f);
    __syncthreads();

    #pragma unroll
    for (int r = 0; r < RB; ++r) acc[r] = b1[t];
    #pragma unroll 8
    for (int j4 = 0; j4 < H / 4; ++j4) {
        float wa = W1[(4*j4+0)*H + t];
        float wb = W1[(4*j4+1)*H + t];
        float wc = W1[(4*j4+2)*H + t];
        float wd = W1[(4*j4+3)*H + t];
        #pragma unroll
        for (int r = 0; r < RB; ++r) {
            float4 hv = *(const float4*)&h0[r * H + 4*j4];
            acc[r] += hv.x*wa + hv.y*wb + hv.z*wc + hv.w*wd;
        }
    }
    #pragma unroll
    for (int r = 0; r < RB; ++r) h1[r * H + t] = fmaxf(acc[r], 0.f);
    __syncthreads();

    for (int i = t; i < RB * F; i += 128) {
        int r = i >> 5, f = i & 31;
        float a = bout[f];
        #pragma unroll 8
        for (int j4 = 0; j4 < H / 4; ++j4) {
            float4 hv = *(const float4*)&h1[r * H + 4*j4];
            a += hv.x*Wout[(4*j4+0)*F + f] + hv.y*Wout[(4*j4+1)*F + f]
               + hv.z*Wout[(4*j4+2)*F + f] + hv.w*Wout[(4*j4+3)*F + f];
        }
        babsT[f * B + r0 + r] = fabsf(a);
    }
}

// ---------------- Kernel B: NW partial sums, LDS-broadcast points ----------------
// Thread = batch row b (512 = whole batch). Block = chunk of CHUNK=20 points.
// Chunk staged in LDS from row-major xbg (640 contiguous floats, no transpose
// needed); inner reads are ds_read_b128 at lane-uniform addresses = pure
// broadcast (0 conflicts). Per-thread state: xq[32]+bv[32]+2 accums ~85 VGPR
// < 128 budget (launch_bounds(512,4)). Inner op = v_sub + v_fma(|.|).
__global__ __launch_bounds__(512, 4) void nw_partial(
    const float* __restrict__ XT,
    const float* __restrict__ babsT,
    const float* __restrict__ xbg,
    const float* __restrict__ ybg,
    float* __restrict__ psw,
    float* __restrict__ pswy)
{
    __shared__ __align__(16) float tile[CHUNK * F];   // 2560 B
    __shared__ float ytile[CHUNK];

    const int b  = threadIdx.x;
    const int n0 = blockIdx.x * CHUNK;

    // stage chunk: 640 contiguous floats + 20 y values (coalesced)
    tile[b] = xbg[n0 * F + b];
    if (b < CHUNK * F - 512) tile[512 + b] = xbg[n0 * F + 512 + b];
    if (b < CHUNK) ytile[b] = ybg[n0 + b];

    // preload row data (independent of LDS, overlaps staging)
    float xq[F], bv[F];
    #pragma unroll
    for (int f = 0; f < F; ++f) {
        xq[f] = XT[f * B + b];          // coalesced 256B/wave, L2-resident
        bv[f] = babsT[f * B + b];
    }
    __syncthreads();

    const float4* t4 = (const float4*)tile;
    float sw = 0.f, swy = 0.f;

    #pragma unroll 5
    for (int j = 0; j < CHUNK; ++j) {
        float da = 0.f, db = 0.f;
        #pragma unroll
        for (int q = 0; q < F / 4; ++q) {
            float4 v = t4[j * (F / 4) + q];   // lane-uniform addr -> broadcast
            da += bv[4*q+0] * fabsf(xq[4*q+0] - v.x);
            db += bv[4*q+1] * fabsf(xq[4*q+1] - v.y);
            da += bv[4*q+2] * fabsf(xq[4*q+2] - v.z);
            db += bv[4*q+3] * fabsf(xq[4*q+3] - v.w);
        }
        float w = __expf(-(da + db));
        sw  += w;
        swy += w * ytile[j];
    }

    psw [blockIdx.x * B + b] = sw;    // coalesced
    pswy[blockIdx.x * B + b] = swy;
}

// ---------------- Kernel C: combine partials, normalize ----------------
__global__ __launch_bounds__(64) void nw_final(
    const float* __restrict__ psw,
    const float* __restrict__ pswy,
    float* __restrict__ out)
{
    const int b = blockIdx.x;
    const int t = threadIdx.x;

    float sw = 0.f, swy = 0.f;
    for (int c = t; c < NBLK; c += 64) {
        sw  += psw [c * B + b];
        swy += pswy[c * B + b];
    }
    #pragma unroll
    for (int off = 32; off > 0; off >>= 1) {
        sw  += __shfl_down(sw,  off);
        swy += __shfl_down(swy, off);
    }
    if (t == 0) out[b] = swy / sw;
}

extern "C" void kernel_launch(void* const* d_in, const int* in_sizes, int n_in,
                              void* d_out, int out_size, void* d_ws, size_t ws_size,
                              hipStream_t stream)
{
    const float* X    = (const float*)d_in[0];
    const float* xbg  = (const float*)d_in[1];
    const float* ybg  = (const float*)d_in[2];
    const float* W0   = (const float*)d_in[3];
    const float* b0   = (const float*)d_in[4];
    const float* W1   = (const float*)d_in[5];
    const float* b1   = (const float*)d_in[6];
    const float* Wout = (const float*)d_in[7];
    const float* bout = (const float*)d_in[8];
    float* out = (float*)d_out;

    float* XT    = (float*)d_ws;              // F*B
    float* babsT = XT + F * B;                // F*B
    float* psw   = babsT + F * B;             // NBLK*B (1 MB)
    float* pswy  = psw + NBLK * B;            // NBLK*B (1 MB)

    prep_kernel<<<MLPBLK, 128, 0, stream>>>(X, W0, b0, W1, b1, Wout, bout, XT, babsT);
    nw_partial<<<NBLK, B, 0, stream>>>(XT, babsT, xbg, ybg, psw, pswy);
    nw_final<<<B, 64, 0, stream>>>(psw, pswy, out);
}